// Round 1
// baseline (562.690 us; speedup 1.0000x reference)
//
#include <hip/hip_runtime.h>

#define HD 2048
#define FD 8192
#define NE 8
#define CAP 512

typedef __attribute__((ext_vector_type(4))) float f32x4;
typedef __attribute__((ext_vector_type(8))) __bf16 bf16x8;

// ---------------- weight f32 -> bf16 conversion ----------------
__global__ __launch_bounds__(256) void cvt_k(const float* __restrict__ src,
                                             __bf16* __restrict__ dst, int n8) {
    int i = blockIdx.x * 256 + threadIdx.x;
    if (i >= n8) return;
    const float* s = src + (size_t)i * 8;
    f32x4 a = *(const f32x4*)s;
    f32x4 b = *(const f32x4*)(s + 4);
    bf16x8 o;
    o[0] = (__bf16)a[0]; o[1] = (__bf16)a[1]; o[2] = (__bf16)a[2]; o[3] = (__bf16)a[3];
    o[4] = (__bf16)b[0]; o[5] = (__bf16)b[1]; o[6] = (__bf16)b[2]; o[7] = (__bf16)b[3];
    *(bf16x8*)(dst + (size_t)i * 8) = o;
}

// ---------------- router: f64 logits, f32-prob top-2 with index tie-break ----------------
__global__ __launch_bounds__(256) void router_k(const float* __restrict__ x,
                                                const float* __restrict__ rw,
                                                int2* __restrict__ experts,
                                                float2* __restrict__ probs, int Ntok) {
    int wave = threadIdx.x >> 6, lane = threadIdx.x & 63;
    int n = blockIdx.x * 4 + wave;
    if (n >= Ntok) return;
    const float* xr = x + (size_t)n * HD;
    double acc[NE];
#pragma unroll
    for (int e = 0; e < NE; e++) acc[e] = 0.0;
    for (int i = 0; i < HD / 64; i++) {
        float xv = xr[lane + 64 * i];
#pragma unroll
        for (int e = 0; e < NE; e++)
            acc[e] += (double)xv * (double)rw[e * HD + lane + 64 * i];
    }
#pragma unroll
    for (int e = 0; e < NE; e++) {
        double v = acc[e];
        for (int off = 32; off > 0; off >>= 1) v += __shfl_xor(v, off);
        acc[e] = v;
    }
    if (lane == 0) {
        double mx = acc[0];
#pragma unroll
        for (int e = 1; e < NE; e++) mx = acc[e] > mx ? acc[e] : mx;
        double s = 0.0;
#pragma unroll
        for (int e = 0; e < NE; e++) s += exp(acc[e] - mx);
        float pf[NE];
#pragma unroll
        for (int e = 0; e < NE; e++) pf[e] = (float)(exp(acc[e] - mx) / s);
        // top-1: strict > keeps lowest index on ties (lax.top_k semantics)
        int e0 = 0; float b0 = pf[0];
#pragma unroll
        for (int e = 1; e < NE; e++) if (pf[e] > b0) { b0 = pf[e]; e0 = e; }
        int e1 = -1; float b1 = -1.0f;
#pragma unroll
        for (int e = 0; e < NE; e++) if (e != e0 && pf[e] > b1) { b1 = pf[e]; e1 = e; }
        experts[n] = make_int2(e0, e1);
        probs[n] = make_float2(b0, b1);
    }
}

// ---------------- capacity scan (slot-major order), single block ----------------
__global__ __launch_bounds__(256) void scan_k(const int2* __restrict__ experts,
                                              int* __restrict__ dest,
                                              int* __restrict__ slot_token, int Ntok) {
    __shared__ int cnts[256][NE];
    int tid = threadIdx.x;
    for (int i = tid; i < NE * CAP; i += 256) slot_token[i] = -1;
    int per = (2 * Ntok) / 256;  // 16
    int base = tid * per;
    int c[NE];
#pragma unroll
    for (int e = 0; e < NE; e++) c[e] = 0;
    int eloc[16];
    for (int i = 0; i < per; i++) {
        int j = base + i;
        int t = j & (Ntok - 1);
        int2 ex = experts[t];
        int e = (j >= Ntok) ? ex.y : ex.x;
        eloc[i] = e;
        c[e]++;
    }
#pragma unroll
    for (int e = 0; e < NE; e++) cnts[tid][e] = c[e];
    __syncthreads();
    if (tid < NE) {
        int run = 0;
        for (int t2 = 0; t2 < 256; t2++) { int v = cnts[t2][tid]; cnts[t2][tid] = run; run += v; }
    }
    __syncthreads();
    int b[NE];
#pragma unroll
    for (int e = 0; e < NE; e++) b[e] = cnts[tid][e];
    for (int i = 0; i < per; i++) {
        int j = base + i;
        int t = j & (Ntok - 1);
        int e = eloc[i];
        int pos = b[e]++;
        if (pos < CAP) {
            int d = e * CAP + pos;
            dest[j] = d;
            slot_token[d] = t;
        } else {
            dest[j] = -1;
        }
    }
}

// ---------------- dispatch: gather tokens into bf16 buffer ----------------
__global__ __launch_bounds__(256) void dispatch_k(const float* __restrict__ x,
                                                  const int* __restrict__ slot_token,
                                                  __bf16* __restrict__ buf) {
    int slot = blockIdx.x;
    int tok = slot_token[slot];
    int idx = threadIdx.x * 8;
    __bf16* drow = buf + (size_t)slot * HD + idx;
    if (tok >= 0) {
        const float* srow = x + (size_t)tok * HD + idx;
        f32x4 a = *(const f32x4*)srow;
        f32x4 b = *(const f32x4*)(srow + 4);
        bf16x8 o;
        o[0] = (__bf16)a[0]; o[1] = (__bf16)a[1]; o[2] = (__bf16)a[2]; o[3] = (__bf16)a[3];
        o[4] = (__bf16)b[0]; o[5] = (__bf16)b[1]; o[6] = (__bf16)b[2]; o[7] = (__bf16)b[3];
        *(bf16x8*)drow = o;
    } else {
        f32x4 z = 0;
        *(f32x4*)drow = z;  // 16B of zero bits == 8 bf16 zeros
    }
}

__device__ inline float gelu_exact(float v) {
    return 0.5f * v * (1.0f + erff(v * 0.70710678118654752f));
}

// ---------------- NT GEMM: C[M,N] = A[M,K] * B[N,K]^T, bf16 in, MFMA ----------------
// EPI=0: h1 = (bf16)gelu(x + bias)   EPI=1: h2 = (f32)(x + bias)
template <int EPI>
__global__ __launch_bounds__(256) void gemm_nt(const __bf16* __restrict__ A,
                                               const __bf16* __restrict__ B,
                                               const float* __restrict__ bias,
                                               void* __restrict__ Cout,
                                               int M, int N, int K) {
    __shared__ __align__(16) __bf16 As[128][72];
    __shared__ __align__(16) __bf16 Bs[128][72];
    int m0 = blockIdx.y * 128, n0 = blockIdx.x * 128;
    int tid = threadIdx.x;
    int wave = tid >> 6, lane = tid & 63;
    int wr = wave >> 1, wc = wave & 1;
    int lrow = lane & 15, lk = (lane >> 4) * 8;

    f32x4 acc[4][4];
#pragma unroll
    for (int m = 0; m < 4; m++)
#pragma unroll
        for (int n = 0; n < 4; n++) acc[m][n] = 0;

    for (int kt = 0; kt < K; kt += 64) {
#pragma unroll
        for (int i = 0; i < 4; i++) {
            int cc = i * 256 + tid;
            int row = cc >> 3, kc = cc & 7;
            *(bf16x8*)&As[row][kc * 8] =
                *(const bf16x8*)&A[(size_t)(m0 + row) * K + kt + kc * 8];
            *(bf16x8*)&Bs[row][kc * 8] =
                *(const bf16x8*)&B[(size_t)(n0 + row) * K + kt + kc * 8];
        }
        __syncthreads();
#pragma unroll
        for (int kk = 0; kk < 2; kk++) {
            bf16x8 af[4], bfr[4];
            int kb = kk * 32 + lk;
#pragma unroll
            for (int m = 0; m < 4; m++)
                af[m] = *(const bf16x8*)&As[wr * 64 + m * 16 + lrow][kb];
#pragma unroll
            for (int n = 0; n < 4; n++)
                bfr[n] = *(const bf16x8*)&Bs[wc * 64 + n * 16 + lrow][kb];
#pragma unroll
            for (int m = 0; m < 4; m++)
#pragma unroll
                for (int n = 0; n < 4; n++)
                    acc[m][n] = __builtin_amdgcn_mfma_f32_16x16x32_bf16(
                        af[m], bfr[n], acc[m][n], 0, 0, 0);
        }
        __syncthreads();
    }

    int col_base = n0 + wc * 64;
    int row_base = m0 + wr * 64 + (lane >> 4) * 4;
#pragma unroll
    for (int n = 0; n < 4; n++) {
        int col = col_base + n * 16 + lrow;
        float bv = bias[col];
#pragma unroll
        for (int m = 0; m < 4; m++) {
            int row0 = row_base + m * 16;
#pragma unroll
            for (int r = 0; r < 4; r++) {
                float v = acc[m][n][r] + bv;
                if (EPI == 0) {
                    ((__bf16*)Cout)[(size_t)(row0 + r) * N + col] = (__bf16)gelu_exact(v);
                } else {
                    ((float*)Cout)[(size_t)(row0 + r) * N + col] = v;
                }
            }
        }
    }
}

// ---------------- combine: out[t] = p0*h2[d0] + p1*h2[d1] ----------------
__global__ __launch_bounds__(256) void combine_k(const float* __restrict__ h2,
                                                 const int* __restrict__ dest,
                                                 const float2* __restrict__ probs,
                                                 float* __restrict__ out, int Ntok) {
    int t = blockIdx.x;
    int d0 = dest[t], d1 = dest[Ntok + t];
    float2 p = probs[t];
    int idx = threadIdx.x * 8;
    f32x4 o0 = 0, o1 = 0;
    if (d0 >= 0) {
        const float* r = h2 + (size_t)d0 * HD + idx;
        o0 += p.x * (*(const f32x4*)r);
        o1 += p.x * (*(const f32x4*)(r + 4));
    }
    if (d1 >= 0) {
        const float* r = h2 + (size_t)d1 * HD + idx;
        o0 += p.y * (*(const f32x4*)r);
        o1 += p.y * (*(const f32x4*)(r + 4));
    }
    float* w = out + (size_t)t * HD + idx;
    *(f32x4*)w = o0;
    *(f32x4*)(w + 4) = o1;
}

extern "C" void kernel_launch(void* const* d_in, const int* in_sizes, int n_in,
                              void* d_out, int out_size, void* d_ws, size_t ws_size,
                              hipStream_t stream) {
    const float* x  = (const float*)d_in[0];
    const float* rw = (const float*)d_in[1];
    const float* w1 = (const float*)d_in[2];
    const float* b1 = (const float*)d_in[3];
    const float* w2 = (const float*)d_in[4];
    const float* b2 = (const float*)d_in[5];
    float* out = (float*)d_out;
    int Ntok = in_sizes[0] / HD;  // 2048

    char* ws = (char*)d_ws;
    __bf16* w1b = (__bf16*)ws;            ws += (size_t)FD * HD * 2;
    __bf16* w2b = (__bf16*)ws;            ws += (size_t)HD * FD * 2;
    __bf16* buf = (__bf16*)ws;            ws += (size_t)NE * CAP * HD * 2;
    __bf16* h1  = (__bf16*)ws;            ws += (size_t)NE * CAP * FD * 2;
    float*  h2  = (float*)ws;             ws += (size_t)NE * CAP * HD * 4;
    int2*   experts = (int2*)ws;          ws += (size_t)Ntok * 8;
    float2* probsb  = (float2*)ws;        ws += (size_t)Ntok * 8;
    int*    dest    = (int*)ws;           ws += (size_t)2 * Ntok * 4;
    int*    slot_token = (int*)ws;        ws += (size_t)NE * CAP * 4;

    int n8 = FD * HD / 8;
    cvt_k<<<n8 / 256, 256, 0, stream>>>(w1, w1b, n8);
    cvt_k<<<n8 / 256, 256, 0, stream>>>(w2, w2b, n8);
    router_k<<<Ntok / 4, 256, 0, stream>>>(x, rw, experts, probsb, Ntok);
    scan_k<<<1, 256, 0, stream>>>(experts, dest, slot_token, Ntok);
    dispatch_k<<<NE * CAP, 256, 0, stream>>>(x, slot_token, buf);
    gemm_nt<0><<<dim3(FD / 128, (NE * CAP) / 128), 256, 0, stream>>>(
        buf, w1b, b1, (void*)h1, NE * CAP, FD, HD);
    gemm_nt<1><<<dim3(HD / 128, (NE * CAP) / 128), 256, 0, stream>>>(
        h1, w2b, b2, (void*)h2, NE * CAP, HD, FD);
    combine_k<<<Ntok, 256, 0, stream>>>(h2, dest, probsb, out, Ntok);
}